// Round 3
// baseline (312.895 us; speedup 1.0000x reference)
//
#include <hip/hip_runtime.h>
#include <hip/hip_bf16.h>
#include <stdint.h>

// scores[b,q,k] = dot(Q[b,q,:],K[b,k,:]) / (max(|Qrow|,eps)*max(|Krow|,eps)); mask==0 -> -1e9
// B=4, Sq=Sk=2048, D=1024, fp32 in/out.
//
// R3: MX-FP8 path (K=128 scaled MFMA, unit scales), BK=128 -> 8 barriers,
//     XOR-swizzled LDS (global_load_lds-compatible) -> 2-way bank aliasing (free).
// Pass 1: fp32 -> fp8 e4m3 into d_ws + fp32 row inv-norms.
// Pass 2: fp8 GEMM via __builtin_amdgcn_mfma_scale_f32_16x16x128_f8f6f4.
// Fallback (ws too small): R1 single-kernel bf16 with LDK=40.

constexpr int B_  = 4;
constexpr int SQ  = 2048;
constexpr int SK  = 2048;
constexpr int D_  = 1024;
constexpr int BM  = 128;
constexpr int BN  = 128;
constexpr int BKF = 128;   // fp8 K-tile (bytes per LDS row)
constexpr int BK  = 32;    // bf16 fallback K-tile

typedef __attribute__((ext_vector_type(8))) short    short8;
typedef __attribute__((ext_vector_type(4))) float    f32x4;
typedef __attribute__((ext_vector_type(4))) int      int4v;
typedef __attribute__((ext_vector_type(8))) int      int8v;
typedef __attribute__((ext_vector_type(4))) unsigned uint4v;
typedef unsigned int u32;

__device__ inline unsigned pack_bf16(float lo, float hi) {
  union { float f; unsigned u; } a, b;
  a.f = lo; b.f = hi;
  return __builtin_amdgcn_perm(b.u, a.u, 0x07060302u);
}

__device__ inline void async_ld16(const void* g, void* l) {
  __builtin_amdgcn_global_load_lds((const __attribute__((address_space(1))) u32*)g,
                                   (__attribute__((address_space(3))) u32*)l, 16, 0, 0);
}

// ---------------- Pass 1: fp32 -> fp8 e4m3 + inv norms ----------------
constexpr int ROWS_Q = B_ * SQ;           // 8192
constexpr int ROWS_T = B_ * (SQ + SK);    // 16384

__global__ __launch_bounds__(256) void convert_fp8(
    const float* __restrict__ Q, const float* __restrict__ Km,
    uint8_t* __restrict__ Qb, uint8_t* __restrict__ Kb,
    float* __restrict__ invQ, float* __restrict__ invK)
{
  const int row  = blockIdx.x * 4 + (threadIdx.x >> 6);
  const int lane = threadIdx.x & 63;

  const float* src; uint8_t* dst; float* inv;
  if (row < ROWS_Q) {
    src = Q  + (size_t)row * D_;
    dst = Qb + (size_t)row * D_;
    inv = invQ + row;
  } else {
    int r = row - ROWS_Q;
    src = Km + (size_t)r * D_;
    dst = Kb + (size_t)r * D_;
    inv = invK + r;
  }

  const f32x4* s4 = (const f32x4*)(src + lane * 16);
  f32x4 v[4];
  #pragma unroll
  for (int i = 0; i < 4; ++i) v[i] = s4[i];

  float ss = 0.0f;
  unsigned p[4];
  #pragma unroll
  for (int i = 0; i < 4; ++i) {
    unsigned d = (unsigned)__builtin_amdgcn_cvt_pk_fp8_f32(v[i].x, v[i].y, 0, false);
    d = (unsigned)__builtin_amdgcn_cvt_pk_fp8_f32(v[i].z, v[i].w, (int)d, true);
    p[i] = d;
    ss += v[i].x*v[i].x + v[i].y*v[i].y + v[i].z*v[i].z + v[i].w*v[i].w;
  }
  uint4v w0 = {p[0], p[1], p[2], p[3]};
  *(uint4v*)(dst + lane * 16) = w0;

  #pragma unroll
  for (int off = 32; off > 0; off >>= 1) ss += __shfl_xor(ss, off);
  if (lane == 0) *inv = 1.0f / fmaxf(sqrtf(ss), 1e-8f);
}

// ---------------- Pass 2: MX-FP8 GEMM, BK=128, swizzled LDS ----------------
// LDS layout: row r (128 B = 8 x 16B chunks); position p holds global chunk p^(r&7).
// Staging lane -> row (lane>>3), pos (lane&7), fetches global chunk (lane&7)^(lane>>3).
// Fragment (16x16x128, lane m=lane&15, quad lq=lane>>4): k-bytes lq*32..lq*32+31 =
// global chunks {2lq, 2lq+1} -> LDS positions {(2lq)^(r&7), (2lq+1)^(r&7)}.
// Bank check: 16-lane phase hits 8 distinct 4-bank groups -> 2-way (free, m136).
__global__ __launch_bounds__(256, 2) void ca_gemm_fp8(
    const uint8_t* __restrict__ Qb,   // [B][SQ][D] fp8
    const uint8_t* __restrict__ Kb,   // [B][SK][D] fp8
    const float* __restrict__ invQ,
    const float* __restrict__ invK,
    const int*   __restrict__ mask,
    float*       __restrict__ out)
{
  __shared__ __align__(16) uint8_t As[BM * BKF];   // 16 KB
  __shared__ __align__(16) uint8_t Bs[BN * BKF];   // 16 KB

  const int tid  = threadIdx.x;
  const int lane = tid & 63;
  const int w    = tid >> 6;
  const int b    = blockIdx.z;
  const int tm0  = blockIdx.y * BM;
  const int tn0  = blockIdx.x * BN;

  const int srow   = lane >> 3;                 // 0..7 within 8-row group
  const int gchunk = (lane & 7) ^ srow;         // swizzled global 16B chunk

  const uint8_t* qrow = Qb + ((size_t)b * SQ + tm0 + w * 32 + srow) * D_ + gchunk * 16;
  const uint8_t* krow = Kb + ((size_t)b * SK + tn0 + w * 32 + srow) * D_ + gchunk * 16;
  const size_t rstep8 = (size_t)8 * D_;         // 8 rows in bytes

  uint8_t* ldsA = As + (size_t)(w * 32) * BKF;
  uint8_t* ldsB = Bs + (size_t)(w * 32) * BKF;

  f32x4 zero4 = {0.0f, 0.0f, 0.0f, 0.0f};
  f32x4 acc[4][4];
  #pragma unroll
  for (int i = 0; i < 4; ++i)
    #pragma unroll
    for (int j = 0; j < 4; ++j) acc[i][j] = zero4;

  const int wm = (w >> 1) * 64;
  const int wn = (w & 1) * 64;
  const int lr = lane & 15;
  const int lq = lane >> 4;

  for (int k0 = 0; k0 < D_; k0 += BKF) {
    __syncthreads();   // previous iter's fragment reads done before overwrite
    #pragma unroll
    for (int i = 0; i < 4; ++i)
      async_ld16(qrow + k0 + i * rstep8, ldsA + i * 8 * BKF);
    #pragma unroll
    for (int i = 0; i < 4; ++i)
      async_ld16(krow + k0 + i * rstep8, ldsB + i * 8 * BKF);
    __syncthreads();   // compiler drains vmcnt before barrier -> tiles visible

    int8v af[4], bf[4];
    #pragma unroll
    for (int t = 0; t < 4; ++t) {
      const int r  = wm + t * 16 + lr;
      const int sw = r & 7;
      const int4v* rp = (const int4v*)(As + (size_t)r * BKF);
      int4v lo = rp[(2 * lq) ^ sw];
      int4v hi = rp[(2 * lq + 1) ^ sw];
      af[t] = (int8v){lo.x, lo.y, lo.z, lo.w, hi.x, hi.y, hi.z, hi.w};
    }
    #pragma unroll
    for (int t = 0; t < 4; ++t) {
      const int r  = wn + t * 16 + lr;
      const int sw = r & 7;
      const int4v* rp = (const int4v*)(Bs + (size_t)r * BKF);
      int4v lo = rp[(2 * lq) ^ sw];
      int4v hi = rp[(2 * lq + 1) ^ sw];
      bf[t] = (int8v){lo.x, lo.y, lo.z, lo.w, hi.x, hi.y, hi.z, hi.w};
    }

    #pragma unroll
    for (int i = 0; i < 4; ++i)
      #pragma unroll
      for (int j = 0; j < 4; ++j)
        acc[i][j] = __builtin_amdgcn_mfma_scale_f32_16x16x128_f8f6f4(
            af[i], bf[j], acc[i][j], 0, 0, 0, 127, 0, 127);  // unit scales (E8M0 127 = 2^0)
  }

  // Epilogue: C/D layout col=lane&15, row=(lane>>4)*4+reg (shape-determined).
  #pragma unroll
  for (int tn = 0; tn < 4; ++tn) {
    const int gc = tn0 + wn + tn * 16 + lr;
    const int mk = mask[b * SK + gc];
    const float ib = invK[b * SK + gc];
    #pragma unroll
    for (int tm = 0; tm < 4; ++tm) {
      const int lrow = wm + tm * 16 + lq * 4;
      #pragma unroll
      for (int r = 0; r < 4; ++r) {
        const float ia = invQ[b * SQ + tm0 + lrow + r];
        float v = mk ? acc[tm][tn][r] * ia * ib : -1000000000.0f;
        out[((size_t)b * SQ + tm0 + lrow + r) * SK + gc] = v;
      }
    }
  }
}

// ---------------- Fallback: single-kernel bf16, LDK=40 ----------------
constexpr int LDK = 40;

__global__ __launch_bounds__(256, 2) void ca_gemm(
    const float* __restrict__ Q, const float* __restrict__ Km,
    const int* __restrict__ mask, float* __restrict__ out)
{
  __shared__ __align__(16) short As[BM * LDK];
  __shared__ __align__(16) short Bs[BN * LDK];
  __shared__ float ssA_part[256];
  __shared__ float ssB_part[256];
  __shared__ float invA[BM];
  __shared__ float invB[BN];

  const int tid  = threadIdx.x;
  const int lane = tid & 63;
  const int w    = tid >> 6;
  const int b    = blockIdx.z;
  const int tm0  = blockIdx.y * BM;
  const int tn0  = blockIdx.x * BN;

  const int ra = tid >> 1;
  const int ka = (tid & 1) * 16;

  const float* qp = Q  + ((size_t)b * SQ + tm0 + ra) * D_ + ka;
  const float* kp = Km + ((size_t)b * SK + tn0 + ra) * D_ + ka;

  f32x4 zero4 = {0.0f, 0.0f, 0.0f, 0.0f};
  f32x4 acc[4][4];
  #pragma unroll
  for (int i = 0; i < 4; ++i)
    #pragma unroll
    for (int j = 0; j < 4; ++j) acc[i][j] = zero4;

  float ssA = 0.0f, ssB = 0.0f;

  const int wm = (w >> 1) * 64;
  const int wn = (w & 1) * 64;
  const int lr = lane & 15;
  const int lq = lane >> 4;

  short* aw = &As[ra * LDK + ka];
  short* bw = &Bs[ra * LDK + ka];

  for (int k0 = 0; k0 < D_; k0 += BK) {
    f32x4 av[4], bv[4];
    #pragma unroll
    for (int i = 0; i < 4; ++i) av[i] = *(const f32x4*)(qp + 4 * i);
    #pragma unroll
    for (int i = 0; i < 4; ++i) bv[i] = *(const f32x4*)(kp + 4 * i);
    qp += BK; kp += BK;

    unsigned pa[8], pb[8];
    #pragma unroll
    for (int i = 0; i < 4; ++i) {
      pa[2*i]   = pack_bf16(av[i].x, av[i].y);
      pa[2*i+1] = pack_bf16(av[i].z, av[i].w);
      pb[2*i]   = pack_bf16(bv[i].x, bv[i].y);
      pb[2*i+1] = pack_bf16(bv[i].z, bv[i].w);
      ssA += av[i].x*av[i].x + av[i].y*av[i].y + av[i].z*av[i].z + av[i].w*av[i].w;
      ssB += bv[i].x*bv[i].x + bv[i].y*bv[i].y + bv[i].z*bv[i].z + bv[i].w*bv[i].w;
    }

    __syncthreads();
    {
      uint4v wa0 = {pa[0], pa[1], pa[2], pa[3]};
      uint4v wa1 = {pa[4], pa[5], pa[6], pa[7]};
      uint4v wb0 = {pb[0], pb[1], pb[2], pb[3]};
      uint4v wb1 = {pb[4], pb[5], pb[6], pb[7]};
      *(uint4v*)(aw)     = wa0;
      *(uint4v*)(aw + 8) = wa1;
      *(uint4v*)(bw)     = wb0;
      *(uint4v*)(bw + 8) = wb1;
    }
    __syncthreads();

    short8 af[4], bf[4];
    #pragma unroll
    for (int t = 0; t < 4; ++t)
      af[t] = *(const short8*)&As[(wm + t * 16 + lr) * LDK + lq * 8];
    #pragma unroll
    for (int t = 0; t < 4; ++t)
      bf[t] = *(const short8*)&Bs[(wn + t * 16 + lr) * LDK + lq * 8];

    #pragma unroll
    for (int i = 0; i < 4; ++i)
      #pragma unroll
      for (int j = 0; j < 4; ++j)
        acc[i][j] = __builtin_amdgcn_mfma_f32_16x16x32_bf16(af[i], bf[j], acc[i][j], 0, 0, 0);
  }

  ssA_part[tid] = ssA;
  ssB_part[tid] = ssB;
  __syncthreads();
  if (tid < BM) {
    float s = ssA_part[2 * tid] + ssA_part[2 * tid + 1];
    invA[tid] = 1.0f / fmaxf(sqrtf(s), 1e-8f);
  } else {
    int r = tid - BM;
    float s = ssB_part[2 * r] + ssB_part[2 * r + 1];
    invB[r] = 1.0f / fmaxf(sqrtf(s), 1e-8f);
  }
  __syncthreads();

  #pragma unroll
  for (int tn = 0; tn < 4; ++tn) {
    const int lc = wn + tn * 16 + lr;
    const int gc = tn0 + lc;
    const int mk = mask[b * SK + gc];
    const float ib = invB[lc];
    #pragma unroll
    for (int tm = 0; tm < 4; ++tm) {
      const int lrow = wm + tm * 16 + lq * 4;
      #pragma unroll
      for (int r = 0; r < 4; ++r) {
        float v = mk ? acc[tm][tn][r] * invA[lrow + r] * ib : -1000000000.0f;
        out[((size_t)b * SQ + tm0 + lrow + r) * SK + gc] = v;
      }
    }
  }
}

extern "C" void kernel_launch(void* const* d_in, const int* in_sizes, int n_in,
                              void* d_out, int out_size, void* d_ws, size_t ws_size,
                              hipStream_t stream) {
  const float* Q    = (const float*)d_in[0];
  const float* Km   = (const float*)d_in[1];
  const int*   mask = (const int*)d_in[2];
  float*       out  = (float*)d_out;

  const size_t nQ   = (size_t)B_ * SQ * D_;   // elements (1 byte each as fp8)
  const size_t nK   = (size_t)B_ * SK * D_;
  const size_t need = nQ + nK + (size_t)B_ * (SQ + SK) * 4;
  if (ws_size >= need) {
    uint8_t* Qb = (uint8_t*)d_ws;
    uint8_t* Kb = Qb + nQ;
    float*   iQ = (float*)(Kb + nK);
    float*   iK = iQ + (size_t)B_ * SQ;
    convert_fp8<<<ROWS_T / 4, 256, 0, stream>>>(Q, Km, Qb, Kb, iQ, iK);
    dim3 grid(SK / BN, SQ / BM, B_);
    ca_gemm_fp8<<<grid, dim3(256), 0, stream>>>(Qb, Kb, iQ, iK, mask, out);
  } else {
    dim3 grid(SK / BN, SQ / BM, B_);
    ca_gemm<<<grid, dim3(256), 0, stream>>>(Q, Km, mask, out);
  }
}

// Round 4
// 161.717 us; speedup vs baseline: 1.9348x; 1.9348x over previous
//
#include <hip/hip_runtime.h>
#include <hip/hip_bf16.h>
#include <stdint.h>

// scores[b,q,k] = dot(Q[b,q,:],K[b,k,:]) / (max(|Qrow|,eps)*max(|Krow|,eps)); mask==0 -> -1e9
// B=4, Sq=Sk=2048, D=1024, fp32 in/out.
//
// R4: back to bf16 (R3 fp8 spilled ~314MB scratch: 8-dword frags too register-hungry).
//  Pass 1: fp32 -> bf16 in d_ws + row inv-norms.
//  Pass 2: bf16 GEMM, BK=64, global_load_lds width=16, XOR-swizzled LDS:
//          row r stores global 16B-chunk c at position c^(r&7)  ->  fragment
//          ds_read_b128 phases hit all 32 banks 2-way (free) vs R2's 8-way.
// Fallback (ws too small): R1 single-kernel bf16, LDK=40.

constexpr int B_  = 4;
constexpr int SQ  = 2048;
constexpr int SK  = 2048;
constexpr int D_  = 1024;
constexpr int BM  = 128;
constexpr int BN  = 128;
constexpr int BK  = 64;    // bf16 K-tile: 128 B rows = 8 x 16B chunks
constexpr int BKf = 32;    // fallback K-tile

typedef __attribute__((ext_vector_type(8))) short    short8;
typedef __attribute__((ext_vector_type(4))) float    f32x4;
typedef __attribute__((ext_vector_type(4))) unsigned uint4v;
typedef unsigned int u32;

__device__ inline unsigned pack_bf16(float lo, float hi) {
  union { float f; unsigned u; } a, b;
  a.f = lo; b.f = hi;
  return __builtin_amdgcn_perm(b.u, a.u, 0x07060302u);
}

__device__ inline void async_ld16(const void* g, void* l) {
  __builtin_amdgcn_global_load_lds((const __attribute__((address_space(1))) u32*)g,
                                   (__attribute__((address_space(3))) u32*)l, 16, 0, 0);
}

// ---------------- Pass 1: convert + norms ----------------
constexpr int ROWS_Q = B_ * SQ;           // 8192
constexpr int ROWS_T = B_ * (SQ + SK);    // 16384

__global__ __launch_bounds__(256) void convert_norm(
    const float* __restrict__ Q, const float* __restrict__ Km,
    unsigned short* __restrict__ Qb, unsigned short* __restrict__ Kb,
    float* __restrict__ invQ, float* __restrict__ invK)
{
  const int row  = blockIdx.x * 4 + (threadIdx.x >> 6);
  const int lane = threadIdx.x & 63;

  const float* src; unsigned short* dst; float* inv;
  if (row < ROWS_Q) {
    src = Q  + (size_t)row * D_;
    dst = Qb + (size_t)row * D_;
    inv = invQ + row;
  } else {
    int r = row - ROWS_Q;
    src = Km + (size_t)r * D_;
    dst = Kb + (size_t)r * D_;
    inv = invK + r;
  }

  const f32x4* s4 = (const f32x4*)(src + lane * 16);
  f32x4 v[4];
  #pragma unroll
  for (int i = 0; i < 4; ++i) v[i] = s4[i];

  float ss = 0.0f;
  unsigned p[8];
  #pragma unroll
  for (int i = 0; i < 4; ++i) {
    p[2*i]   = pack_bf16(v[i].x, v[i].y);
    p[2*i+1] = pack_bf16(v[i].z, v[i].w);
    ss += v[i].x*v[i].x + v[i].y*v[i].y + v[i].z*v[i].z + v[i].w*v[i].w;
  }
  uint4v w0 = {p[0], p[1], p[2], p[3]};
  uint4v w1 = {p[4], p[5], p[6], p[7]};
  uint4v* d4 = (uint4v*)(dst + lane * 16);
  d4[0] = w0; d4[1] = w1;

  #pragma unroll
  for (int off = 32; off > 0; off >>= 1) ss += __shfl_xor(ss, off);
  if (lane == 0) *inv = 1.0f / fmaxf(sqrtf(ss), 1e-8f);
}

// ---------------- Pass 2: bf16 GEMM, BK=64, swizzled LDS ----------------
__global__ __launch_bounds__(256, 2) void ca_gemm_bf(
    const unsigned short* __restrict__ Qb,   // [B][SQ][D] bf16
    const unsigned short* __restrict__ Kb,   // [B][SK][D] bf16
    const float* __restrict__ invQ,
    const float* __restrict__ invK,
    const int*   __restrict__ mask,
    float*       __restrict__ out)
{
  __shared__ __align__(16) unsigned short As[BM * BK];   // 16 KB
  __shared__ __align__(16) unsigned short Bs[BN * BK];   // 16 KB

  const int tid  = threadIdx.x;
  const int lane = tid & 63;
  const int w    = tid >> 6;
  const int b    = blockIdx.z;
  const int tm0  = blockIdx.y * BM;
  const int tn0  = blockIdx.x * BN;

  // Staging: one async_ld16 covers 8 rows x 128 B. lane -> row (lane>>3), pos (lane&7);
  // fetch global chunk (lane&7)^(lane>>3) so LDS pos p of row r holds chunk p^(r&7).
  const int srow   = lane >> 3;
  const int gchunk = (lane & 7) ^ srow;

  const char* qrow = (const char*)(Qb + ((size_t)b * SQ + tm0 + w * 32 + srow) * D_) + gchunk * 16;
  const char* krow = (const char*)(Kb + ((size_t)b * SK + tn0 + w * 32 + srow) * D_) + gchunk * 16;
  const size_t rstep8 = (size_t)8 * D_ * 2;   // 8 rows in bytes

  unsigned short* ldsA = &As[(size_t)(w * 32) * BK];
  unsigned short* ldsB = &Bs[(size_t)(w * 32) * BK];

  f32x4 zero4 = {0.0f, 0.0f, 0.0f, 0.0f};
  f32x4 acc[4][4];
  #pragma unroll
  for (int i = 0; i < 4; ++i)
    #pragma unroll
    for (int j = 0; j < 4; ++j) acc[i][j] = zero4;

  const int wm = (w >> 1) * 64;
  const int wn = (w & 1) * 64;
  const int lr = lane & 15;
  const int lq = lane >> 4;

  for (int k0 = 0; k0 < D_; k0 += BK) {
    __syncthreads();   // previous iter's fragment reads done before overwrite
    const size_t kb = (size_t)k0 * 2;
    #pragma unroll
    for (int i = 0; i < 4; ++i)
      async_ld16(qrow + kb + i * rstep8, ldsA + i * 8 * BK);
    #pragma unroll
    for (int i = 0; i < 4; ++i)
      async_ld16(krow + kb + i * rstep8, ldsB + i * 8 * BK);
    __syncthreads();   // compiler drains vmcnt before barrier -> tiles visible

    // Two k-steps of 32 within the 64-wide tile; chunk s*4+lq at swizzled pos.
    #pragma unroll
    for (int s = 0; s < 2; ++s) {
      short8 af[4], bf[4];
      #pragma unroll
      for (int t = 0; t < 4; ++t) {
        const int r = wm + t * 16 + lr;
        af[t] = *(const short8*)&As[(size_t)r * BK + (size_t)(((s * 4 + lq) ^ (r & 7)) * 8)];
      }
      #pragma unroll
      for (int t = 0; t < 4; ++t) {
        const int r = wn + t * 16 + lr;
        bf[t] = *(const short8*)&Bs[(size_t)r * BK + (size_t)(((s * 4 + lq) ^ (r & 7)) * 8)];
      }
      #pragma unroll
      for (int i = 0; i < 4; ++i)
        #pragma unroll
        for (int j = 0; j < 4; ++j)
          acc[i][j] = __builtin_amdgcn_mfma_f32_16x16x32_bf16(af[i], bf[j], acc[i][j], 0, 0, 0);
    }
  }

  // Epilogue: C/D col=lane&15, row=(lane>>4)*4+reg.
  #pragma unroll
  for (int tn = 0; tn < 4; ++tn) {
    const int gc = tn0 + wn + tn * 16 + lr;
    const int mk = mask[b * SK + gc];
    const float ib = invK[b * SK + gc];
    #pragma unroll
    for (int tm = 0; tm < 4; ++tm) {
      const int lrow = wm + tm * 16 + lq * 4;
      #pragma unroll
      for (int r = 0; r < 4; ++r) {
        const float ia = invQ[b * SQ + tm0 + lrow + r];
        float v = mk ? acc[tm][tn][r] * ia * ib : -1000000000.0f;
        out[((size_t)b * SQ + tm0 + lrow + r) * SK + gc] = v;
      }
    }
  }
}

// ---------------- Fallback: single-kernel bf16, LDK=40 ----------------
constexpr int LDK = 40;

__global__ __launch_bounds__(256, 2) void ca_gemm(
    const float* __restrict__ Q, const float* __restrict__ Km,
    const int* __restrict__ mask, float* __restrict__ out)
{
  __shared__ __align__(16) short As[BM * LDK];
  __shared__ __align__(16) short Bs[BN * LDK];
  __shared__ float ssA_part[256];
  __shared__ float ssB_part[256];
  __shared__ float invA[BM];
  __shared__ float invB[BN];

  const int tid  = threadIdx.x;
  const int lane = tid & 63;
  const int w    = tid >> 6;
  const int b    = blockIdx.z;
  const int tm0  = blockIdx.y * BM;
  const int tn0  = blockIdx.x * BN;

  const int ra = tid >> 1;
  const int ka = (tid & 1) * 16;

  const float* qp = Q  + ((size_t)b * SQ + tm0 + ra) * D_ + ka;
  const float* kp = Km + ((size_t)b * SK + tn0 + ra) * D_ + ka;

  f32x4 zero4 = {0.0f, 0.0f, 0.0f, 0.0f};
  f32x4 acc[4][4];
  #pragma unroll
  for (int i = 0; i < 4; ++i)
    #pragma unroll
    for (int j = 0; j < 4; ++j) acc[i][j] = zero4;

  float ssA = 0.0f, ssB = 0.0f;

  const int wm = (w >> 1) * 64;
  const int wn = (w & 1) * 64;
  const int lr = lane & 15;
  const int lq = lane >> 4;

  short* aw = &As[ra * LDK + ka];
  short* bw = &Bs[ra * LDK + ka];

  for (int k0 = 0; k0 < D_; k0 += BKf) {
    f32x4 av[4], bv[4];
    #pragma unroll
    for (int i = 0; i < 4; ++i) av[i] = *(const f32x4*)(qp + 4 * i);
    #pragma unroll
    for (int i = 0; i < 4; ++i) bv[i] = *(const f32x4*)(kp + 4 * i);
    qp += BKf; kp += BKf;

    unsigned pa[8], pb[8];
    #pragma unroll
    for (int i = 0; i < 4; ++i) {
      pa[2*i]   = pack_bf16(av[i].x, av[i].y);
      pa[2*i+1] = pack_bf16(av[i].z, av[i].w);
      pb[2*i]   = pack_bf16(bv[i].x, bv[i].y);
      pb[2*i+1] = pack_bf16(bv[i].z, bv[i].w);
      ssA += av[i].x*av[i].x + av[i].y*av[i].y + av[i].z*av[i].z + av[i].w*av[i].w;
      ssB += bv[i].x*bv[i].x + bv[i].y*bv[i].y + bv[i].z*bv[i].z + bv[i].w*bv[i].w;
    }

    __syncthreads();
    {
      uint4v wa0 = {pa[0], pa[1], pa[2], pa[3]};
      uint4v wa1 = {pa[4], pa[5], pa[6], pa[7]};
      uint4v wb0 = {pb[0], pb[1], pb[2], pb[3]};
      uint4v wb1 = {pb[4], pb[5], pb[6], pb[7]};
      *(uint4v*)(aw)     = wa0;
      *(uint4v*)(aw + 8) = wa1;
      *(uint4v*)(bw)     = wb0;
      *(uint4v*)(bw + 8) = wb1;
    }
    __syncthreads();

    short8 af[4], bf[4];
    #pragma unroll
    for (int t = 0; t < 4; ++t)
      af[t] = *(const short8*)&As[(wm + t * 16 + lr) * LDK + lq * 8];
    #pragma unroll
    for (int t = 0; t < 4; ++t)
      bf[t] = *(const short8*)&Bs[(wn + t * 16 + lr) * LDK + lq * 8];

    #pragma unroll
    for (int i = 0; i < 4; ++i)
      #pragma unroll
      for (int j = 0; j < 4; ++j)
        acc[i][j] = __builtin_amdgcn_mfma_f32_16x16x32_bf16(af[i], bf[j], acc[i][j], 0, 0, 0);
  }

  ssA_part[tid] = ssA;
  ssB_part[tid] = ssB;
  __syncthreads();
  if (tid < BM) {
    float s = ssA_part[2 * tid] + ssA_part[2 * tid + 1];
    invA[tid] = 1.0f / fmaxf(sqrtf(s), 1e-8f);
  } else {
    int r = tid - BM;
    float s = ssB_part[2 * r] + ssB_part[2 * r + 1];
    invB[r] = 1.0f / fmaxf(sqrtf(s), 1e-8f);
  }
  __syncthreads();

  #pragma unroll
  for (int tn = 0; tn < 4; ++tn) {
    const int lc = wn + tn * 16 + lr;
    const int gc = tn0 + lc;
    const int mk = mask[b * SK + gc];
    const float ib = invB[lc];
    #pragma unroll
    for (int tm = 0; tm < 4; ++tm) {
      const int lrow = wm + tm * 16 + lq * 4;
      #pragma unroll
      for (int r = 0; r < 4; ++r) {
        float v = mk ? acc[tm][tn][r] * invA[lrow + r] * ib : -1000000000.0f;
        out[((size_t)b * SQ + tm0 + lrow + r) * SK + gc] = v;
      }
    }
  }
}

extern "C" void kernel_launch(void* const* d_in, const int* in_sizes, int n_in,
                              void* d_out, int out_size, void* d_ws, size_t ws_size,
                              hipStream_t stream) {
  const float* Q    = (const float*)d_in[0];
  const float* Km   = (const float*)d_in[1];
  const int*   mask = (const int*)d_in[2];
  float*       out  = (float*)d_out;

  const size_t nQ   = (size_t)B_ * SQ * D_;        // elements
  const size_t nK   = (size_t)B_ * SK * D_;
  const size_t need = (nQ + nK) * 2 + (size_t)B_ * (SQ + SK) * 4;
  if (ws_size >= need) {
    unsigned short* Qb = (unsigned short*)d_ws;
    unsigned short* Kb = Qb + nQ;
    float*          iQ = (float*)(Kb + nK);
    float*          iK = iQ + (size_t)B_ * SQ;
    convert_norm<<<ROWS_T / 4, 256, 0, stream>>>(Q, Km, Qb, Kb, iQ, iK);
    dim3 grid(SK / BN, SQ / BM, B_);
    ca_gemm_bf<<<grid, dim3(256), 0, stream>>>(Qb, Kb, iQ, iK, mask, out);
  } else {
    dim3 grid(SK / BN, SQ / BM, B_);
    ca_gemm<<<grid, dim3(256), 0, stream>>>(Q, Km, mask, out);
  }
}